// Round 2
// baseline (105.855 us; speedup 1.0000x reference)
//
#include <hip/hip_runtime.h>

// PCEN with 10 smoothing rates.
// x: (B,F,T) f32 ; s_log: (R,F) ; alpha_log/delta_log/r_log: (F)
// out: (B,R,F,T) f32
//
// One wave (64 lanes) owns one (b, rate, f) row of T=4000.
// Constant-coefficient linear recurrence y_t = a*y_{t-1} + s*x_t, y_0 = x_0
// (seed carry=x_0 works since a+s=1). Per 256-element chunk:
//   - each lane loads float4 (coalesced), local 4-elem scan (zero input),
//   - 6-step shuffle scan over lane carries with powers a^4..a^128,
//   - per-element fixup y_j = a^(j+1)*y_in + l_j,
//   - PCEN epilogue: smooth=(eps+m)^(-alpha), out=(x*smooth+delta)^r - delta^r
//     via native exp2/log2 (__builtin_* to avoid glibc math.h macro clash).

constexpr int B_ = 16, F_ = 128, T_ = 4000, R_ = 10;
constexpr float EPS_ = 1e-5f;
constexpr int TPB = 256;            // 4 waves / block
constexpr int WPB = TPB / 64;

__global__ __launch_bounds__(TPB) void pcen_kernel(
    const float* __restrict__ x,
    const float* __restrict__ s_log,
    const float* __restrict__ alpha_log,
    const float* __restrict__ delta_log,
    const float* __restrict__ r_log,
    float* __restrict__ out)
{
    const int wid  = blockIdx.x * WPB + (threadIdx.x >> 6);
    const int lane = threadIdx.x & 63;

    // wid -> (b, f, rate): consecutive waves share (b,f) -> x row reuse in L1/L2
    const int b    = wid / (F_ * R_);
    const int rem  = wid - b * (F_ * R_);
    const int f    = rem / R_;
    const int rate = rem - f * R_;

    const float s     = __builtin_expf(s_log[rate * F_ + f]);
    const float a     = 1.0f - s;
    const float alpha = __builtin_expf(alpha_log[f]);
    const float delta = __builtin_expf(delta_log[f]);
    const float r     = __builtin_expf(r_log[f]);
    const float delta_r = __builtin_exp2f(r * __builtin_log2f(delta));

    const float a2 = a * a, a3 = a2 * a, a4 = a2 * a2;
    const float a8 = a4 * a4, a16 = a8 * a8, a32 = a16 * a16;
    const float a64 = a32 * a32, a128 = a64 * a64;

    const float* xrow = x   + (size_t)(b * F_ + f) * T_;
    float*       orow = out + (size_t)((b * R_ + rate) * F_ + f) * T_;

    float carry = xrow[0];   // y_{-1} := x_0  (a+s=1 makes y_0 = x_0)

    for (int t0 = 0; t0 < T_; t0 += 256) {
        const int t = t0 + lane * 4;
        float4 v = make_float4(0.f, 0.f, 0.f, 0.f);
        if (t < T_) v = *reinterpret_cast<const float4*>(xrow + t);

        // local scan with zero incoming state
        const float l0 = s * v.x;
        const float l1 = fmaf(a, l0, s * v.y);
        const float l2 = fmaf(a, l1, s * v.z);
        const float l3 = fmaf(a, l2, s * v.w);

        float Y = l3;
        if (lane == 0) Y = fmaf(a4, carry, Y);   // fold chunk carry into lane 0

        // Hillis-Steele inclusive scan, constant multiplier a^4 per lane
        float up;
        up = __shfl_up(Y, 1);  if (lane >= 1)  Y = fmaf(a4,   up, Y);
        up = __shfl_up(Y, 2);  if (lane >= 2)  Y = fmaf(a8,   up, Y);
        up = __shfl_up(Y, 4);  if (lane >= 4)  Y = fmaf(a16,  up, Y);
        up = __shfl_up(Y, 8);  if (lane >= 8)  Y = fmaf(a32,  up, Y);
        up = __shfl_up(Y, 16); if (lane >= 16) Y = fmaf(a64,  up, Y);
        up = __shfl_up(Y, 32); if (lane >= 32) Y = fmaf(a128, up, Y);

        float yin = __shfl_up(Y, 1);
        if (lane == 0) yin = carry;
        carry = __shfl(Y, 63);                   // chunk-exit state, broadcast

        // per-element smoother values
        const float m0 = fmaf(a,  yin, l0);
        const float m1 = fmaf(a2, yin, l1);
        const float m2 = fmaf(a3, yin, l2);
        const float m3 = fmaf(a4, yin, l3);

        if (t < T_) {
            float4 o;
            {
                const float sm = __builtin_exp2f(-alpha * __builtin_log2f(EPS_ + m0));
                o.x = __builtin_exp2f(r * __builtin_log2f(fmaf(v.x, sm, delta))) - delta_r;
            }
            {
                const float sm = __builtin_exp2f(-alpha * __builtin_log2f(EPS_ + m1));
                o.y = __builtin_exp2f(r * __builtin_log2f(fmaf(v.y, sm, delta))) - delta_r;
            }
            {
                const float sm = __builtin_exp2f(-alpha * __builtin_log2f(EPS_ + m2));
                o.z = __builtin_exp2f(r * __builtin_log2f(fmaf(v.z, sm, delta))) - delta_r;
            }
            {
                const float sm = __builtin_exp2f(-alpha * __builtin_log2f(EPS_ + m3));
                o.w = __builtin_exp2f(r * __builtin_log2f(fmaf(v.w, sm, delta))) - delta_r;
            }
            *reinterpret_cast<float4*>(orow + t) = o;
        }
    }
}

extern "C" void kernel_launch(void* const* d_in, const int* in_sizes, int n_in,
                              void* d_out, int out_size, void* d_ws, size_t ws_size,
                              hipStream_t stream) {
    const float* x         = (const float*)d_in[0];
    const float* s_log     = (const float*)d_in[1];
    const float* alpha_log = (const float*)d_in[2];
    const float* delta_log = (const float*)d_in[3];
    const float* r_log     = (const float*)d_in[4];
    float* out = (float*)d_out;

    const int n_waves = B_ * F_ * R_;          // 20480
    const int blocks  = n_waves / WPB;         // 5120
    pcen_kernel<<<blocks, TPB, 0, stream>>>(x, s_log, alpha_log, delta_log, r_log, out);
}

// Round 3
// 90.845 us; speedup vs baseline: 1.1652x; 1.1652x over previous
//
#include <hip/hip_runtime.h>

// PCEN with 10 smoothing rates. x:(B,F,T) f32 -> out:(B,R,F,T) f32
//
// One wave owns one (b,rate,f) row of T=4000.
// y_t = a*y_{t-1} + s*x_t, y_0 = x_0 (seed carry=x_0, a+s=1).
// Per 512-element chunk: lane loads 8 floats (2x float4), local 8-elem scan,
// 6-step shuffle scan over lane carries (multipliers a^8..a^256),
// per-element fixup, PCEN epilogue via native exp2/log2, nontemporal stores.
//
// R2 changes vs R1 (105.9us):
//  - rate-major wave mapping: block's 4 waves write 4 CONSECUTIVE 16KB output
//    rows (64KB dense) instead of rows 2MB apart -> denser HBM write streams.
//    x re-reads across rates served by L3 (x=32.8MB << 256MB).
//  - V=4 -> V=8 per lane: halves chunk count, shuffle ops, serial carry chain.
//  - nontemporal stores: out is never re-read; keep x resident in L2.

typedef float f32x4 __attribute__((ext_vector_type(4)));

constexpr int B_ = 16, F_ = 128, T_ = 4000, R_ = 10;
constexpr float EPS_ = 1e-5f;
constexpr int TPB = 256;            // 4 waves / block
constexpr int WPB = TPB / 64;

__global__ __launch_bounds__(TPB) void pcen_kernel(
    const float* __restrict__ x,
    const float* __restrict__ s_log,
    const float* __restrict__ alpha_log,
    const float* __restrict__ delta_log,
    const float* __restrict__ r_log,
    float* __restrict__ out)
{
    const int wid  = blockIdx.x * WPB + (threadIdx.x >> 6);
    const int lane = threadIdx.x & 63;

    // rate-major: wid = ((b*R + rate)*F + f) -> consecutive waves write
    // consecutive output rows.
    const int b    = wid / (R_ * F_);
    const int rem  = wid - b * (R_ * F_);
    const int rate = rem / F_;
    const int f    = rem - rate * F_;

    const float s     = __builtin_expf(s_log[rate * F_ + f]);
    const float a     = 1.0f - s;
    const float alpha = __builtin_expf(alpha_log[f]);
    const float delta = __builtin_expf(delta_log[f]);
    const float r     = __builtin_expf(r_log[f]);
    const float delta_r = __builtin_exp2f(r * __builtin_log2f(delta));

    const float a2 = a * a,     a3 = a2 * a,    a4 = a2 * a2;
    const float a5 = a4 * a,    a6 = a4 * a2,   a7 = a4 * a3,   a8 = a4 * a4;
    const float a16 = a8 * a8,  a32 = a16 * a16, a64 = a32 * a32;
    const float a128 = a64 * a64, a256 = a128 * a128;

    const float* xrow = x   + (size_t)(b * F_ + f) * T_;
    float*       orow = out + (size_t)((b * R_ + rate) * F_ + f) * T_;

    float carry = xrow[0];   // y_{-1} := x_0  (a+s=1 makes y_0 = x_0)

    auto pcen1 = [&](float xv, float m) -> float {
        const float sm = __builtin_exp2f(-alpha * __builtin_log2f(EPS_ + m));
        return __builtin_exp2f(r * __builtin_log2f(fmaf(xv, sm, delta))) - delta_r;
    };

    for (int t0 = 0; t0 < T_; t0 += 512) {
        const int t = t0 + lane * 8;
        const bool act = (t < T_);           // T_ % 8 == 0: active lanes are full
        float4 v0 = make_float4(0.f, 0.f, 0.f, 0.f);
        float4 v1 = make_float4(0.f, 0.f, 0.f, 0.f);
        if (act) {
            v0 = *reinterpret_cast<const float4*>(xrow + t);
            v1 = *reinterpret_cast<const float4*>(xrow + t + 4);
        }

        // local scan with zero incoming state
        const float l0 = s * v0.x;
        const float l1 = fmaf(a, l0, s * v0.y);
        const float l2 = fmaf(a, l1, s * v0.z);
        const float l3 = fmaf(a, l2, s * v0.w);
        const float l4 = fmaf(a, l3, s * v1.x);
        const float l5 = fmaf(a, l4, s * v1.y);
        const float l6 = fmaf(a, l5, s * v1.z);
        const float l7 = fmaf(a, l6, s * v1.w);

        float Y = l7;
        if (lane == 0) Y = fmaf(a8, carry, Y);   // fold chunk carry into lane 0

        // Hillis-Steele inclusive scan, per-lane segment multiplier a^8
        float up;
        up = __shfl_up(Y, 1);  if (lane >= 1)  Y = fmaf(a8,   up, Y);
        up = __shfl_up(Y, 2);  if (lane >= 2)  Y = fmaf(a16,  up, Y);
        up = __shfl_up(Y, 4);  if (lane >= 4)  Y = fmaf(a32,  up, Y);
        up = __shfl_up(Y, 8);  if (lane >= 8)  Y = fmaf(a64,  up, Y);
        up = __shfl_up(Y, 16); if (lane >= 16) Y = fmaf(a128, up, Y);
        up = __shfl_up(Y, 32); if (lane >= 32) Y = fmaf(a256, up, Y);

        float yin = __shfl_up(Y, 1);
        if (lane == 0) yin = carry;
        carry = __shfl(Y, 63);                   // chunk-exit state, broadcast

        if (act) {
            const float m0 = fmaf(a,  yin, l0);
            const float m1 = fmaf(a2, yin, l1);
            const float m2 = fmaf(a3, yin, l2);
            const float m3 = fmaf(a4, yin, l3);
            const float m4 = fmaf(a5, yin, l4);
            const float m5 = fmaf(a6, yin, l5);
            const float m6 = fmaf(a7, yin, l6);
            const float m7 = fmaf(a8, yin, l7);

            f32x4 o0, o1;
            o0.x = pcen1(v0.x, m0);
            o0.y = pcen1(v0.y, m1);
            o0.z = pcen1(v0.z, m2);
            o0.w = pcen1(v0.w, m3);
            o1.x = pcen1(v1.x, m4);
            o1.y = pcen1(v1.y, m5);
            o1.z = pcen1(v1.z, m6);
            o1.w = pcen1(v1.w, m7);
            __builtin_nontemporal_store(o0, reinterpret_cast<f32x4*>(orow + t));
            __builtin_nontemporal_store(o1, reinterpret_cast<f32x4*>(orow + t + 4));
        }
    }
}

extern "C" void kernel_launch(void* const* d_in, const int* in_sizes, int n_in,
                              void* d_out, int out_size, void* d_ws, size_t ws_size,
                              hipStream_t stream) {
    const float* x         = (const float*)d_in[0];
    const float* s_log     = (const float*)d_in[1];
    const float* alpha_log = (const float*)d_in[2];
    const float* delta_log = (const float*)d_in[3];
    const float* r_log     = (const float*)d_in[4];
    float* out = (float*)d_out;

    const int n_waves = B_ * R_ * F_;          // 20480
    const int blocks  = n_waves / WPB;         // 5120
    pcen_kernel<<<blocks, TPB, 0, stream>>>(x, s_log, alpha_log, delta_log, r_log, out);
}